// Round 3
// baseline (5819.257 us; speedup 1.0000x reference)
//
#include <hip/hip_runtime.h>

#define T_STEPS 4096
#define BATCH   128
#define HID     256

__device__ __forceinline__ float fast_tanh(float z) {
    // tanh(z) = 1 - 2/(exp(2z)+1); exact saturation, ~1e-6 abs err
    float e = __expf(2.0f * z);
    return 1.0f - 2.0f / (e + 1.0f);
}

// broadcast lane l's value of v to all lanes via SGPR (uniform result)
__device__ __forceinline__ float rlane(float v, int l) {
    return __uint_as_float(__builtin_amdgcn_readlane(__float_as_uint(v), l));
}

#define RPT16(M, q) M(q,0) M(q,1) M(q,2) M(q,3) M(q,4) M(q,5) M(q,6) M(q,7) \
                    M(q,8) M(q,9) M(q,10) M(q,11) M(q,12) M(q,13) M(q,14) M(q,15)

// 256 threads = 4 waves, 1 wave/SIMD -> 512-reg unified budget per wave.
// Thread t owns W2 column t (256 floats in registers). Each wave computes the
// full h1 itself (4 values/lane) and broadcasts via v_readlane -> SGPR operand
// of v_fmac: the 65536-MAC GEMV touches NO LDS and needs NO barrier.
__global__ __launch_bounds__(256, 1)
void odenet_kernel(const float* __restrict__ x,
                   const float* __restrict__ W1, const float* __restrict__ b1,
                   const float* __restrict__ W2, const float* __restrict__ b2,
                   const float* __restrict__ W3, const float* __restrict__ b3,
                   float* __restrict__ out)
{
    const int b    = blockIdx.x;   // batch element
    const int t    = threadIdx.x;  // 0..255 = output column j
    const int lane = t & 63;
    const int wid  = t >> 6;

    __shared__ float x_lds[T_STEPS];  // 16 KB input column
    __shared__ float red[4];          // per-wave partials of the y-update dot

    for (int i = t; i < T_STEPS; i += 256) x_lds[i] = x[i * BATCH + b];

    // ---- W2 column t in 64 named float4 registers ----
    const float* Wcol = W2 + t;
    #define DECLW(q,g) float4 w4_##q##_##g;
    RPT16(DECLW,0) RPT16(DECLW,1) RPT16(DECLW,2) RPT16(DECLW,3)
    #define LOADW(q,g) \
        w4_##q##_##g.x = Wcol[(64*(q) + 4*(g) + 0) * HID]; \
        w4_##q##_##g.y = Wcol[(64*(q) + 4*(g) + 1) * HID]; \
        w4_##q##_##g.z = Wcol[(64*(q) + 4*(g) + 2) * HID]; \
        w4_##q##_##g.w = Wcol[(64*(q) + 4*(g) + 3) * HID];
    RPT16(LOADW,0) RPT16(LOADW,1) RPT16(LOADW,2) RPT16(LOADW,3)

    // ---- layer-1 params for this lane's 4 hidden indices k = lane + 64q ----
    const float w1a0 = W1[lane      ], w1a1 = W1[lane +  64],
                w1a2 = W1[lane + 128], w1a3 = W1[lane + 192];
    const float w1b0 = W1[HID + lane      ], w1b1 = W1[HID + lane +  64],
                w1b2 = W1[HID + lane + 128], w1b3 = W1[HID + lane + 192];
    const float b1_0 = b1[lane      ], b1_1 = b1[lane +  64],
                b1_2 = b1[lane + 128], b1_3 = b1[lane + 192];

    const float b2v = b2[t];
    const float w3v = W3[t];
    const float b3v = b3[0];

    float y = 0.0f;
    __syncthreads();

    #pragma unroll 1
    for (int n = 0; n < T_STEPS; ++n) {
        if (t == 0) out[n * BATCH + b] = y;   // emit y_n (pre-update)

        // layer 1: this wave's full h1, 4 values per lane (k = lane + 64q)
        const float xt  = x_lds[n];
        const float hr0 = fast_tanh(fmaf(y, w1a0, fmaf(xt, w1b0, b1_0)));
        const float hr1 = fast_tanh(fmaf(y, w1a1, fmaf(xt, w1b1, b1_1)));
        const float hr2 = fast_tanh(fmaf(y, w1a2, fmaf(xt, w1b2, b1_2)));
        const float hr3 = fast_tanh(fmaf(y, w1a3, fmaf(xt, w1b3, b1_3)));

        // layer 2 GEMV: 256 readlane-broadcasts + 256 fmac, 4 indep chains
        float acc0 = 0.f, acc1 = 0.f, acc2 = 0.f, acc3 = 0.f;
        #define FMA4(q,g) { \
            const float s0 = rlane(hr##q, 4*(g) + 0); \
            const float s1 = rlane(hr##q, 4*(g) + 1); \
            const float s2 = rlane(hr##q, 4*(g) + 2); \
            const float s3 = rlane(hr##q, 4*(g) + 3); \
            acc0 = fmaf(s0, w4_##q##_##g.x, acc0); \
            acc1 = fmaf(s1, w4_##q##_##g.y, acc1); \
            acc2 = fmaf(s2, w4_##q##_##g.z, acc2); \
            acc3 = fmaf(s3, w4_##q##_##g.w, acc3); }
        RPT16(FMA4,0) RPT16(FMA4,1) RPT16(FMA4,2) RPT16(FMA4,3)

        // layer-2 tanh + layer-3 contribution of this column
        const float qv = (acc0 + acc1) + (acc2 + acc3) + b2v;
        const float h2 = fast_tanh(qv);
        float p = h2 * w3v;

        // wave-sum of p, then cross-wave combine via 4 LDS words
        #pragma unroll
        for (int m = 32; m >= 1; m >>= 1) p += __shfl_xor(p, m, 64);
        if (lane == 0) red[wid] = p;
        __syncthreads();

        // all threads update y identically (same fp ops -> same value)
        y += (red[0] + red[1] + red[2] + red[3]) + b3v;
    }
}

extern "C" void kernel_launch(void* const* d_in, const int* in_sizes, int n_in,
                              void* d_out, int out_size, void* d_ws, size_t ws_size,
                              hipStream_t stream) {
    const float* x  = (const float*)d_in[0];
    const float* W1 = (const float*)d_in[1];
    const float* b1 = (const float*)d_in[2];
    const float* W2 = (const float*)d_in[3];
    const float* b2 = (const float*)d_in[4];
    const float* W3 = (const float*)d_in[5];
    const float* b3 = (const float*)d_in[6];
    float* out = (float*)d_out;

    odenet_kernel<<<dim3(BATCH), dim3(256), 0, stream>>>(x, W1, b1, W2, b2, W3, b3, out);
}

// Round 4
// 4213.073 us; speedup vs baseline: 1.3812x; 1.3812x over previous
//
#include <hip/hip_runtime.h>

#define T_STEPS 4096
#define BATCH   128
#define HID     256

typedef float f4 __attribute__((ext_vector_type(4)));

__device__ __forceinline__ float fast_tanh(float z) {
    // tanh(z) = 1 - 2/(exp(2z)+1); exact saturation, ~1e-6 abs err
    float e = __expf(2.0f * z);
    return 1.0f - 2.0f / (e + 1.0f);
}

#define RPT32(M) M(0) M(1) M(2) M(3) M(4) M(5) M(6) M(7) \
                 M(8) M(9) M(10) M(11) M(12) M(13) M(14) M(15) \
                 M(16) M(17) M(18) M(19) M(20) M(21) M(22) M(23) \
                 M(24) M(25) M(26) M(27) M(28) M(29) M(30) M(31)

// 512 threads = 8 waves (2/SIMD). Wave w owns k-slice [32w, 32w+32).
// Lane l owns 4 CONTIGUOUS output columns 4l..4l+3 -> each uniform
// ds_read_b128 of h1 (4 k-values) feeds 16 FMAs (4x reuse), and the
// partial write is a single coalesced ds_write_b128.
// Weights: 32 float4 per thread, passed through an opaque asm identity so
// the allocator cannot rematerialize the (invariant) global loads -- the
// failure mode of rounds 1-3 (VGPR_Count 80-144, weights re-read from L2
// every step).
__global__ __launch_bounds__(512, 2)
void odenet_kernel(const float* __restrict__ x,
                   const float* __restrict__ W1, const float* __restrict__ b1,
                   const float* __restrict__ W2, const float* __restrict__ b2,
                   const float* __restrict__ W3, const float* __restrict__ b3,
                   float* __restrict__ out)
{
    const int b = blockIdx.x;     // batch element
    const int t = threadIdx.x;    // 0..511
    const int w = t >> 6;         // wave id 0..7  (k-slice)
    const int l = t & 63;         // lane: columns 4l..4l+3

    __shared__ float x_lds[T_STEPS];            // 16 KB
    __shared__ float h1_lds[HID];               // 1 KB
    __shared__ float part[8][HID];              // 8 KB  part[w][j]
    __shared__ __align__(16) float red[4];      // wave partials of y-dot

    for (int i = t; i < T_STEPS; i += 512) x_lds[i] = x[i * BATCH + b];

    // ---- weights: rows 32w..32w+31, columns 4l..4l+3 (coalesced f4 loads)
    #define DECLQ(i) \
        f4 wq##i = *(const f4*)(W2 + (32*w + (i)) * HID + 4*l); \
        asm volatile("" : "+v"(wq##i));   /* block rematerialization */
    RPT32(DECLQ)

    // ---- layer-1 / combine parameters (threads 0..255 use index t) ----
    const int  j   = t & 255;
    const float w1a = W1[j];          // W1[0][j]
    const float w1b = W1[HID + j];    // W1[1][j]
    const float b1v = b1[j];
    const float b2v = b2[j];
    const float w3v = W3[j];
    const float b3v = b3[0];

    float y = 0.0f;
    __syncthreads();

    #pragma unroll 1
    for (int n = 0; n < T_STEPS; ++n) {
        // ---- emit y_n; layer 1 (threads 0..255) ----
        if (t == 256) out[n * BATCH + b] = y;
        if (t < 256) {
            float xt = x_lds[n];
            h1_lds[t] = fast_tanh(fmaf(y, w1a, fmaf(xt, w1b, b1v)));
        }
        __syncthreads();   // B1: h1 ready

        // ---- GEMV partial: k in [32w,32w+32), columns 4l..4l+3 ----
        f4 acc = {0.f, 0.f, 0.f, 0.f};
        const f4* h4 = ((const f4*)h1_lds) + 8 * w;   // uniform per wave
        #define GQUAD(g, q0, q1, q2, q3) { \
            f4 hq = h4[g]; \
            acc += hq.x * wq##q0; \
            acc += hq.y * wq##q1; \
            acc += hq.z * wq##q2; \
            acc += hq.w * wq##q3; }
        GQUAD(0,  0,  1,  2,  3)
        GQUAD(1,  4,  5,  6,  7)
        GQUAD(2,  8,  9, 10, 11)
        GQUAD(3, 12, 13, 14, 15)
        GQUAD(4, 16, 17, 18, 19)
        GQUAD(5, 20, 21, 22, 23)
        GQUAD(6, 24, 25, 26, 27)
        GQUAD(7, 28, 29, 30, 31)

        *(f4*)(&part[w][4 * l]) = acc;   // coalesced ds_write_b128
        __syncthreads();   // B2: partials ready

        // ---- combine 8 k-slices, layer-2 tanh, layer-3 dot ----
        if (t < 256) {
            float s = ((part[0][t] + part[1][t]) + (part[2][t] + part[3][t]))
                    + ((part[4][t] + part[5][t]) + (part[6][t] + part[7][t]))
                    + b2v;
            float h2 = fast_tanh(s);
            float p  = h2 * w3v;
            #pragma unroll
            for (int m = 32; m >= 1; m >>= 1) p += __shfl_xor(p, m, 64);
            if (l == 0) red[w] = p;      // waves 0..3
        }
        __syncthreads();   // B3: red ready

        // all threads update y identically
        f4 r = *(const f4*)red;          // uniform ds_read_b128
        y += ((r.x + r.y) + (r.z + r.w)) + b3v;
    }
}

extern "C" void kernel_launch(void* const* d_in, const int* in_sizes, int n_in,
                              void* d_out, int out_size, void* d_ws, size_t ws_size,
                              hipStream_t stream) {
    const float* x  = (const float*)d_in[0];
    const float* W1 = (const float*)d_in[1];
    const float* b1 = (const float*)d_in[2];
    const float* W2 = (const float*)d_in[3];
    const float* b2 = (const float*)d_in[4];
    const float* W3 = (const float*)d_in[5];
    const float* b3 = (const float*)d_in[6];
    float* out = (float*)d_out;

    odenet_kernel<<<dim3(BATCH), dim3(512), 0, stream>>>(x, W1, b1, W2, b2, W3, b3, out);
}

// Round 6
// 3576.511 us; speedup vs baseline: 1.6271x; 1.1780x over previous
//
#include <hip/hip_runtime.h>

#define T_STEPS 4096
#define BATCH   128
#define HID     256

typedef float f4 __attribute__((ext_vector_type(4)));

__device__ __forceinline__ float fast_tanh(float z) {
    // tanh(z) = 1 - 2/(exp(2z)+1); exact saturation, ~1e-6 abs err
    float e = __expf(2.0f * z);
    return 1.0f - 2.0f / (e + 1.0f);
}

__device__ __forceinline__ float rlane(float v, int l) {
    return __uint_as_float(__builtin_amdgcn_readlane(__float_as_uint(v), l));
}

// one level of the canonical GCN wave64 DPP reduction (VALU pipe, ~4cyc/level
// vs ~30cyc/level for ds_bpermute-based __shfl_xor). DPP controls must be
// integer-constant expressions -> template parameters.
template <int CTRL, int ROW_MASK>
__device__ __forceinline__ float dpp_add(float x) {
    int s = __builtin_amdgcn_update_dpp(0, __float_as_int(x), CTRL, ROW_MASK, 0xf, false);
    return x + __int_as_float(s);
}

#define RPT16(M) M(0) M(1) M(2) M(3) M(4) M(5) M(6) M(7) \
                 M(8) M(9) M(10) M(11) M(12) M(13) M(14) M(15)

// 1024 threads = 16 waves (4/SIMD). Wave w owns k-slice [16w,16w+16);
// lane l owns columns 4l..4l+3 -> 64 weights/thread (16 f4 ~ 110 total VGPR,
// small enough that the allocator keeps them in arch VGPRs -- rounds 1-4
// showed it demotes 128+ floats/thread).
// h1 is computed IN-WAVE (lane l computes k=16w+(l&15), redundant x4) and
// broadcast via v_readlane -> SGPR operand of v_fmac: the h-distribution
// needs NO LDS and NO barrier. Only 2 barriers/step remain.
__global__ __launch_bounds__(1024, 4)
void odenet_kernel(const float* __restrict__ x,
                   const float* __restrict__ W1, const float* __restrict__ b1,
                   const float* __restrict__ W2, const float* __restrict__ b2,
                   const float* __restrict__ W3, const float* __restrict__ b3,
                   float* __restrict__ out)
{
    const int b = blockIdx.x;    // batch element
    const int t = threadIdx.x;   // 0..1023
    const int w = t >> 6;        // wave 0..15: k-slice [16w,16w+16)
    const int l = t & 63;        // lane: columns 4l..4l+3
    const int k = 16 * w + (l & 15);   // this lane's h1 index (x4 redundant)

    __shared__ float x_lds[T_STEPS];       // 16 KB
    __shared__ float part[16][HID];        // 16 KB  part[w][j]
    __shared__ __align__(16) float red[4]; // per-combine-wave y-dot partials

    for (int i = t; i < T_STEPS; i += 1024) x_lds[i] = x[i * BATCH + b];

    // ---- W2 slice: rows 16w..16w+15, cols 4l..4l+3 (16 f4, coalesced) ----
    #define DECLQ(i) \
        f4 wq##i = *(const f4*)(W2 + (16*w + (i)) * HID + 4*l); \
        asm volatile("" : "+v"(wq##i));
    RPT16(DECLQ)

    // ---- layer-1 params for this lane's k ----
    const float w1a = W1[k];
    const float w1b = W1[HID + k];
    const float b1v = b1[k];

    // ---- combine params (threads 0..255, col j = t) ----
    const float b2v = (t < 256) ? b2[t] : 0.f;
    const float w3v = (t < 256) ? W3[t] : 0.f;
    const float b3v = b3[0];

    float y = 0.0f;
    __syncthreads();

    #pragma unroll 1
    for (int n = 0; n < T_STEPS; ++n) {
        if (t == 1023) out[n * BATCH + b] = y;   // emit y_n (pre-update)

        // ---- layer 1, in-wave (no barrier) ----
        const float xt = x_lds[n];
        const float h  = fast_tanh(fmaf(y, w1a, fmaf(xt, w1b, b1v)));

        // ---- GEMV: 16 readlane broadcasts + 64 fmac ----
        f4 acc = {0.f, 0.f, 0.f, 0.f};
        #define STEPK(i) { const float s = rlane(h, i); acc += s * wq##i; }
        RPT16(STEPK)
        *(f4*)(&part[w][4 * l]) = acc;     // coalesced ds_write_b128
        __syncthreads();                   // B1: partials ready

        // ---- combine (threads 0..255): col sums, tanh, w3-dot, DPP reduce ----
        if (t < 256) {
            float s0 = 0.f, s1 = 0.f, s2 = 0.f, s3 = 0.f;
            #pragma unroll
            for (int p = 0; p < 4; ++p) {
                s0 += part[4*p + 0][t];
                s1 += part[4*p + 1][t];
                s2 += part[4*p + 2][t];
                s3 += part[4*p + 3][t];
            }
            float h2 = fast_tanh(((s0 + s1) + (s2 + s3)) + b2v);
            float p  = h2 * w3v;
            // canonical wave64 DPP reduce: total lands in lane 63
            p = dpp_add<0x111, 0xf>(p);   // row_shr:1
            p = dpp_add<0x112, 0xf>(p);   // row_shr:2
            p = dpp_add<0x114, 0xf>(p);   // row_shr:4
            p = dpp_add<0x118, 0xf>(p);   // row_shr:8
            p = dpp_add<0x142, 0xa>(p);   // row_bcast:15 (rows 1,3)
            p = dpp_add<0x143, 0xc>(p);   // row_bcast:31 (rows 2,3)
            if (l == 63) red[w] = p;      // combine waves w = 0..3
        }
        __syncthreads();                   // B2: red ready

        // all threads update y identically
        f4 r = *(const f4*)red;            // uniform ds_read_b128
        y += ((r.x + r.y) + (r.z + r.w)) + b3v;
    }
}

extern "C" void kernel_launch(void* const* d_in, const int* in_sizes, int n_in,
                              void* d_out, int out_size, void* d_ws, size_t ws_size,
                              hipStream_t stream) {
    const float* x  = (const float*)d_in[0];
    const float* W1 = (const float*)d_in[1];
    const float* b1 = (const float*)d_in[2];
    const float* W2 = (const float*)d_in[3];
    const float* b2 = (const float*)d_in[4];
    const float* W3 = (const float*)d_in[5];
    const float* b3 = (const float*)d_in[6];
    float* out = (float*)d_out;

    odenet_kernel<<<dim3(BATCH), dim3(1024), 0, stream>>>(x, W1, b1, W2, b2, W3, b3, out);
}